// Round 14
// baseline (513.457 us; speedup 1.0000x reference)
//
#include <hip/hip_runtime.h>
#include <hip/hip_bf16.h>
#include <math.h>

typedef short v8s __attribute__((ext_vector_type(8)));
typedef float v4f __attribute__((ext_vector_type(4)));
typedef float v2f __attribute__((ext_vector_type(2)));
typedef unsigned short u16x4 __attribute__((ext_vector_type(4)));

__device__ __forceinline__ unsigned short f2bf(float f) {
    unsigned int u = __float_as_uint(f);
    u += 0x7fff + ((u >> 16) & 1);   // round-to-nearest-even
    return (unsigned short)(u >> 16);
}
__device__ __forceinline__ float bf2f(unsigned short h) {
    return __uint_as_float(((unsigned int)h) << 16);
}
__device__ __forceinline__ unsigned char f2fp8(float f) {
    int e = __builtin_amdgcn_cvt_pk_fp8_f32(f, f, 0, false);
    return (unsigned char)(e & 0xff);
}
// cross-lane add via DPP (VALU-only); ctrl must be a compile-time constant.
template<int CTRL>
__device__ __forceinline__ float dpp_xadd(float x) {
    int y = __builtin_amdgcn_mov_dpp(__float_as_int(x), CTRL, 0xF, 0xF, true);
    return x + __int_as_float(y);
}

struct GraphPtrs { const int* dst[6]; const int* src[6]; const float* sim[6]; };
struct Ptr3f { const float* p[3]; };
struct PrepArgs {
    const float* adapt_w; const float* q_w; const float* k_w; const float* v_w;
    const float* a_w; const float* head_w;
    const float* q_b; const float* k_b; const float* v_b;
    unsigned short* adapt_wt; unsigned short* W3; unsigned short* a_wt;
    unsigned short* head_wt; float* bias768;
};

// ---------------- fused weight prep: all transposes/conversions + bias concat in ONE dispatch ----------------
__global__ __launch_bounds__(256)
void prep_all_kernel(PrepArgs pa)
{
    __shared__ float tile[32][33];
    const int bid = blockIdx.x;
    const float* W; unsigned short* Wt; int K, N, k0, n0;

    if (bid < 384) {            // adapt: 3 mats, K=512,N=256, 128 tiles each
        int m = bid >> 7, r = bid & 127;
        W = pa.adapt_w + (size_t)m * 512 * 256; Wt = pa.adapt_wt + (size_t)m * 512 * 256;
        K = 512; N = 256; k0 = (r >> 3) * 32; n0 = (r & 7) * 32;
    } else if (bid < 1536) {    // qkv: 18 sections (lt,sec), 64 tiles each
        int b2 = bid - 384, zz = b2 >> 6, r = b2 & 63;
        int lt = zz / 3, sec = zz - lt * 3;
        W = (sec == 0 ? pa.q_w : sec == 1 ? pa.k_w : pa.v_w) + (size_t)lt * 65536;
        Wt = pa.W3 + ((size_t)lt * 768 + sec * 256) * 256;
        K = 256; N = 256; k0 = (r >> 3) * 32; n0 = (r & 7) * 32;
    } else if (bid < 1920) {    // a: 6 mats, 64 tiles each
        int b2 = bid - 1536, m = b2 >> 6, r = b2 & 63;
        W = pa.a_w + (size_t)m * 65536; Wt = pa.a_wt + (size_t)m * 65536;
        K = 256; N = 256; k0 = (r >> 3) * 32; n0 = (r & 7) * 32;
    } else if (bid < 2176) {    // head: 512x512, 256 tiles
        int r = bid - 1920;
        W = pa.head_w; Wt = pa.head_wt;
        K = 512; N = 512; k0 = (r >> 4) * 32; n0 = (r & 15) * 32;
    } else {                    // bias768 concat (whole block takes this path; no barrier needed)
        int i = (bid - 2176) * 256 + threadIdx.x;
        if (i < 6 * 768) {
            int lt = i / 768, c = i - lt * 768;
            int sec = c >> 8, cc = c & 255;
            const float* s = sec == 0 ? pa.q_b : sec == 1 ? pa.k_b : pa.v_b;
            pa.bias768[i] = s[lt * 256 + cc];
        }
        return;
    }

    const int x = threadIdx.x & 31, y = threadIdx.x >> 5;
    #pragma unroll
    for (int j = 0; j < 4; ++j)
        tile[y + 8 * j][x] = W[(size_t)(k0 + y + 8 * j) * N + n0 + x];
    __syncthreads();
    #pragma unroll
    for (int j = 0; j < 4; ++j)
        Wt[(size_t)(n0 + y + 8 * j) * K + k0 + x] = f2bf(tile[x][y + 8 * j]);
}

// ---------------- CSR build (all 6 etypes fused) ----------------
__global__ void hist6_kernel(GraphPtrs gp, int* __restrict__ deg6)
{
    constexpr int doff[6] = {0, 10000, 30000, 35000, 55000, 60000};
    const int ei = blockIdx.y;
    int e = blockIdx.x * 256 + threadIdx.x;
    if (e < 100000) atomicAdd(&deg6[doff[ei] + gp.dst[ei][e]], 1);
}

__global__ __launch_bounds__(256)
void scan6_kernel(const int* __restrict__ deg6, int* __restrict__ rp6, int* __restrict__ cursor6)
{
    constexpr int ndv[6]   = {10000, 20000, 5000, 20000, 5000, 10000};
    constexpr int doff[6]  = {0, 10000, 30000, 35000, 55000, 60000};
    constexpr int rpoff[6] = {0, 10001, 30002, 35003, 55004, 60005};
    const int b = blockIdx.x;
    const int nd = ndv[b];
    const int* deg = deg6 + doff[b];
    int* rowptr = rp6 + rpoff[b];
    int* cursor = cursor6 + doff[b];
    const int t = threadIdx.x, lane = t & 63, w = t >> 6;
    __shared__ int wsum[4];
    int carry = 0;
    for (int base = 0; base < nd; base += 1024) {
        int i0 = base + t * 4;
        int x0 = 0, x1 = 0, x2 = 0, x3 = 0;
        if (i0 + 3 < nd) {
            int4 v = *(const int4*)(deg + i0);
            x0 = v.x; x1 = v.y; x2 = v.z; x3 = v.w;
        } else {
            if (i0 < nd) x0 = deg[i0];
            if (i0 + 1 < nd) x1 = deg[i0 + 1];
            if (i0 + 2 < nd) x2 = deg[i0 + 2];
            if (i0 + 3 < nd) x3 = deg[i0 + 3];
        }
        int s1 = x0 + x1, s2 = s1 + x2, tot = s2 + x3;
        int inc = tot;
        #pragma unroll
        for (int o = 1; o < 64; o <<= 1) {
            int y = __shfl_up(inc, o, 64);
            if (lane >= o) inc += y;
        }
        if (lane == 63) wsum[w] = inc;
        __syncthreads();
        int woff = 0;
        #pragma unroll
        for (int ww = 0; ww < 4; ++ww) if (ww < w) woff += wsum[ww];
        int ebase = carry + woff + inc - tot;
        if (i0 < nd)     { rowptr[i0] = ebase;          cursor[i0] = ebase; }
        if (i0 + 1 < nd) { rowptr[i0 + 1] = ebase + x0; cursor[i0 + 1] = ebase + x0; }
        if (i0 + 2 < nd) { rowptr[i0 + 2] = ebase + s1; cursor[i0 + 2] = ebase + s1; }
        if (i0 + 3 < nd) { rowptr[i0 + 3] = ebase + s2; cursor[i0 + 3] = ebase + s2; }
        carry += wsum[0] + wsum[1] + wsum[2] + wsum[3];
        __syncthreads();
    }
    if (t == 0) rowptr[nd] = carry;
}

// scatter: pack (src, sim) into one int2 in CSR order
__global__ void scatter6_kernel(GraphPtrs gp, int* __restrict__ cursor6,
                                int2* __restrict__ csr_es6)
{
    constexpr int doff[6] = {0, 10000, 30000, 35000, 55000, 60000};
    const int ei = blockIdx.y;
    int e = blockIdx.x * 256 + threadIdx.x;
    if (e < 100000) {
        int j = atomicAdd(&cursor6[doff[ei] + gp.dst[ei][e]], 1);
        int2 es; es.x = gp.src[ei][e]; es.y = __float_as_int(gp.sim[ei][e]);
        csr_es6[(size_t)ei * 100000 + j] = es;
    }
}

// ---------------- MFMA GEMM core, fp32 A (converted on the fly), optional bf16 side-write ----------------
__device__ __forceinline__ void gemm_core(const float* __restrict__ A,
    const unsigned short* __restrict__ Wt, int M, int K, int bm, int bn,
    unsigned short* __restrict__ As, unsigned short* __restrict__ Bs, v4f acc[4][4],
    unsigned short* __restrict__ fout)
{
    const int tid = threadIdx.x;
    const int sr = tid >> 1, sc = (tid & 1) * 16;
    const int arow = bm + sr;
    const bool aok = arow < M;
    const float* ap = A + (size_t)arow * K + sc;
    const unsigned short* bp = Wt + (size_t)(bn + sr) * K + sc;
    const int lane = tid & 63, w = tid >> 6, wr = w >> 1, wc = w & 1;
    const int l16 = lane & 15, lg = lane >> 4;
    const int abase = (wr * 64 + l16) * 32 + lg * 8;
    const int bbase = (wc * 64 + l16) * 32 + lg * 8;

    for (int k0 = 0; k0 < K; k0 += 32) {
        float4 a0 = {0,0,0,0}, a1 = a0, a2 = a0, a3 = a0;
        if (aok) {
            a0 = *(const float4*)(ap + k0);
            a1 = *(const float4*)(ap + k0 + 4);
            a2 = *(const float4*)(ap + k0 + 8);
            a3 = *(const float4*)(ap + k0 + 12);
        }
        uint4 b0 = *(const uint4*)(bp + k0);
        uint4 b1 = *(const uint4*)(bp + k0 + 8);

        if (k0) __syncthreads();

        uint4 w0, w1;
        w0.x = (unsigned int)f2bf(a0.x) | ((unsigned int)f2bf(a0.y) << 16);
        w0.y = (unsigned int)f2bf(a0.z) | ((unsigned int)f2bf(a0.w) << 16);
        w0.z = (unsigned int)f2bf(a1.x) | ((unsigned int)f2bf(a1.y) << 16);
        w0.w = (unsigned int)f2bf(a1.z) | ((unsigned int)f2bf(a1.w) << 16);
        w1.x = (unsigned int)f2bf(a2.x) | ((unsigned int)f2bf(a2.y) << 16);
        w1.y = (unsigned int)f2bf(a2.z) | ((unsigned int)f2bf(a2.w) << 16);
        w1.z = (unsigned int)f2bf(a3.x) | ((unsigned int)f2bf(a3.y) << 16);
        w1.w = (unsigned int)f2bf(a3.z) | ((unsigned int)f2bf(a3.w) << 16);
        if (fout && aok) {
            *(uint4*)(fout + (size_t)arow * K + k0 + sc)     = w0;
            *(uint4*)(fout + (size_t)arow * K + k0 + sc + 8) = w1;
        }
        *(uint4*)&As[sr * 32 + sc]     = w0;
        *(uint4*)&As[sr * 32 + sc + 8] = w1;
        *(uint4*)&Bs[sr * 32 + sc]     = b0;
        *(uint4*)&Bs[sr * 32 + sc + 8] = b1;
        __syncthreads();

        v8s af[4], bfr[4];
        #pragma unroll
        for (int f = 0; f < 4; ++f) af[f] = *(const v8s*)&As[abase + f * 512];
        #pragma unroll
        for (int f = 0; f < 4; ++f) bfr[f] = *(const v8s*)&Bs[bbase + f * 512];
        #pragma unroll
        for (int i = 0; i < 4; ++i)
            #pragma unroll
            for (int j = 0; j < 4; ++j)
                acc[i][j] = __builtin_amdgcn_mfma_f32_16x16x32_bf16(af[i], bfr[j], acc[i][j], 0, 0, 0);
    }
}

// ---------------- MFMA GEMM core, bf16 A — direct global->LDS DMA staging ----------------
__device__ __forceinline__ void gemm_core_bf(const unsigned short* __restrict__ A,
    const unsigned short* __restrict__ Wt, int M, int K, int bm, int bn,
    unsigned short* __restrict__ As, unsigned short* __restrict__ Bs, v4f acc[4][4])
{
    const int tid = threadIdx.x;
    const int lane = tid & 63, w = tid >> 6, wr = w >> 1, wc = w & 1;
    const int l16 = lane & 15, lg = lane >> 4;
    const int abase = (wr * 64 + l16) * 32 + lg * 8;
    const int bbase = (wc * 64 + l16) * 32 + lg * 8;

    const int r0 = 32 * w + (lane >> 2);
    const int cb = (lane & 3) * 8;
    const unsigned short* ag0 = A  + (size_t)(bm + r0) * K + cb;
    const unsigned short* ag1 = A  + (size_t)(bm + r0 + 16) * K + cb;
    const unsigned short* bg0 = Wt + (size_t)(bn + r0) * K + cb;
    const unsigned short* bg1 = Wt + (size_t)(bn + r0 + 16) * K + cb;
    const bool aok0 = (bm + r0) < M, aok1 = (bm + r0 + 16) < M;
    unsigned short* al0 = As + (32 * w) * 32;
    unsigned short* al1 = As + (32 * w + 16) * 32;
    unsigned short* bl0 = Bs + (32 * w) * 32;
    unsigned short* bl1 = Bs + (32 * w + 16) * 32;

    for (int k0 = 0; k0 < K; k0 += 32) {
        if (k0) __syncthreads();
        if (aok0) __builtin_amdgcn_global_load_lds(
            (const __attribute__((address_space(1))) void*)(ag0 + k0),
            (__attribute__((address_space(3))) void*)al0, 16, 0, 0);
        if (aok1) __builtin_amdgcn_global_load_lds(
            (const __attribute__((address_space(1))) void*)(ag1 + k0),
            (__attribute__((address_space(3))) void*)al1, 16, 0, 0);
        __builtin_amdgcn_global_load_lds(
            (const __attribute__((address_space(1))) void*)(bg0 + k0),
            (__attribute__((address_space(3))) void*)bl0, 16, 0, 0);
        __builtin_amdgcn_global_load_lds(
            (const __attribute__((address_space(1))) void*)(bg1 + k0),
            (__attribute__((address_space(3))) void*)bl1, 16, 0, 0);
        __syncthreads();

        v8s af[4], bfr[4];
        #pragma unroll
        for (int f = 0; f < 4; ++f) af[f] = *(const v8s*)&As[abase + f * 512];
        #pragma unroll
        for (int f = 0; f < 4; ++f) bfr[f] = *(const v8s*)&Bs[bbase + f * 512];
        #pragma unroll
        for (int i = 0; i < 4; ++i)
            #pragma unroll
            for (int j = 0; j < 4; ++j)
                acc[i][j] = __builtin_amdgcn_mfma_f32_16x16x32_bf16(af[i], bfr[j], acc[i][j], 0, 0, 0);
    }
}

// ---- adapt: h[t] = feats[t] @ adapt_w[t] + adapt_b[t]  (bf16 out; side-writes bf16 feat0) ----
__global__ __launch_bounds__(256)
void adapt_gemm3(Ptr3f A3, const unsigned short* __restrict__ Wt3,
                 const float* __restrict__ bias3, unsigned short* __restrict__ hbf,
                 unsigned short* __restrict__ fbf)
{
    constexpr int Ms[3] = {20000, 10000, 5000};
    constexpr size_t hoff[3] = {0, 20000ull * 256, 30000ull * 256};
    const int z = blockIdx.z;
    const int M = Ms[z];
    const int bm = blockIdx.y * 128, bn = blockIdx.x * 128;
    if (bm >= M) return;
    __shared__ unsigned short As[128 * 32], Bs[128 * 32];
    v4f acc[4][4] = {};
    unsigned short* fout = (z == 0 && blockIdx.x == 0) ? fbf : nullptr;
    gemm_core(A3.p[z], Wt3 + (size_t)z * 256 * 512, M, 512, bm, bn, As, Bs, acc, fout);

    const int lane = threadIdx.x & 63, w = threadIdx.x >> 6;
    const int wr = w >> 1, wc = w & 1, l16 = lane & 15, lg = lane >> 4;
    const int row0 = bm + wr * 64, col0 = bn + wc * 64;
    const float* bias = bias3 + z * 256;
    unsigned short* Cb = hbf + hoff[z];
    float bv[4];
    #pragma unroll
    for (int fn = 0; fn < 4; ++fn) bv[fn] = bias[col0 + fn * 16 + l16];
    #pragma unroll
    for (int fm = 0; fm < 4; ++fm)
        #pragma unroll
        for (int i = 0; i < 4; ++i) {
            int gm = row0 + fm * 16 + lg * 4 + i;
            if (gm >= M) continue;
            #pragma unroll
            for (int fn = 0; fn < 4; ++fn)
                Cb[(size_t)gm * 256 + col0 + fn * 16 + l16] = f2bf(acc[fm][fn][i] + bv[fn]);
        }
}

// ---- qkv: row layout (1024 B/node): q 256xbf16 | kv 512B lane-interleaved fp8 ----
__global__ __launch_bounds__(256)
void qkv_gemm3(const unsigned short* __restrict__ hbf, const unsigned short* __restrict__ W3l,
               const float* __restrict__ bias768l, unsigned char* __restrict__ qkvb)
{
    constexpr int Ms[3] = {20000, 10000, 5000};
    constexpr size_t hoff[3] = {0, 20000ull * 256, 30000ull * 256};
    constexpr size_t qoffB[3] = {0, 20000ull * 1024, 30000ull * 1024};
    const int z = blockIdx.z;
    const int M = Ms[z];
    const int bm = blockIdx.y * 128, bn = blockIdx.x * 128;
    if (bm >= M) return;
    __shared__ unsigned short As[128 * 32], Bs[128 * 32];
    v4f acc[4][4] = {};
    gemm_core_bf(hbf + hoff[z], W3l + (size_t)z * 768 * 256, M, 256, bm, bn, As, Bs, acc);

    const int lane = threadIdx.x & 63, w = threadIdx.x >> 6;
    const int wr = w >> 1, wc = w & 1, l16 = lane & 15, lg = lane >> 4;
    const int row0 = bm + wr * 64, col0 = bn + wc * 64;
    const float* bias = bias768l + z * 768;
    unsigned char* base = qkvb + qoffB[z];
    float bv[4];
    #pragma unroll
    for (int fn = 0; fn < 4; ++fn) bv[fn] = bias[col0 + fn * 16 + l16];
    #pragma unroll
    for (int fm = 0; fm < 4; ++fm)
        #pragma unroll
        for (int i = 0; i < 4; ++i) {
            int gm = row0 + fm * 16 + lg * 4 + i;
            if (gm >= M) continue;
            #pragma unroll
            for (int fn = 0; fn < 4; ++fn) {
                int c = col0 + fn * 16 + l16;
                float val = acc[fm][fn][i] + bv[fn];
                unsigned char* rowp = base + (size_t)gm * 1024;
                if (c < 256) {
                    *(unsigned short*)(rowp + 2 * c) = f2bf(val);
                } else if (c < 512) {
                    int j = c - 256;
                    rowp[512 + 8 * (j >> 2) + (j & 3)] = f2fp8(val);
                } else {
                    int j = c - 512;
                    rowp[512 + 8 * (j >> 2) + 4 + (j & 3)] = f2fp8(val);
                }
            }
        }
}

// ---- a: h[t] = blend(0.5*agg[t]@a_w[l,t] + a_b[l,t], h[t])  (bf16 h in/out) ----
__global__ __launch_bounds__(256)
void a_gemm3(const unsigned short* __restrict__ aggbf, const unsigned short* __restrict__ Wtl,
             const float* __restrict__ biasl, const float* __restrict__ skipl,
             unsigned short* __restrict__ hbf)
{
    constexpr int Ms[3] = {20000, 10000, 5000};
    constexpr size_t hoff[3] = {0, 20000ull * 256, 30000ull * 256};
    const int z = blockIdx.z;
    const int M = Ms[z];
    const int bm = blockIdx.y * 128, bn = blockIdx.x * 128;
    if (bm >= M) return;
    __shared__ unsigned short As[128 * 32], Bs[128 * 32];
    v4f acc[4][4] = {};
    gemm_core_bf(aggbf + hoff[z], Wtl + (size_t)z * 65536, M, 256, bm, bn, As, Bs, acc);

    const int lane = threadIdx.x & 63, w = threadIdx.x >> 6;
    const int wr = w >> 1, wc = w & 1, l16 = lane & 15, lg = lane >> 4;
    const int row0 = bm + wr * 64, col0 = bn + wc * 64;
    const float* bias = biasl + z * 256;
    unsigned short* Cb = hbf + hoff[z];
    float sv = skipl[z];
    float alpha = 1.0f / (1.0f + expf(-sv));
    float beta = 1.0f - alpha;
    float bv[4];
    #pragma unroll
    for (int fn = 0; fn < 4; ++fn) bv[fn] = bias[col0 + fn * 16 + l16];
    #pragma unroll
    for (int fm = 0; fm < 4; ++fm)
        #pragma unroll
        for (int i = 0; i < 4; ++i) {
            int gm = row0 + fm * 16 + lg * 4 + i;
            if (gm >= M) continue;
            #pragma unroll
            for (int fn = 0; fn < 4; ++fn) {
                size_t idx = (size_t)gm * 256 + col0 + fn * 16 + l16;
                float val = acc[fm][fn][i] * 0.5f + bv[fn];
                val = alpha * val + beta * bf2f(Cb[idx]);
                Cb[idx] = f2bf(val);
            }
        }
}

// ---- final: out = fbf(bf16 feats[0]) @ head_w + cvec ----
__global__ __launch_bounds__(256)
void head_gemm(const unsigned short* __restrict__ A, const unsigned short* __restrict__ Wt,
               const float* __restrict__ bias, float* __restrict__ C)
{
    const int M = 20000, N = 512, K = 512;
    const int bm = blockIdx.y * 128, bn = blockIdx.x * 128;
    if (bm >= M) return;
    __shared__ unsigned short As[128 * 32], Bs[128 * 32];
    v4f acc[4][4] = {};
    gemm_core_bf(A, Wt, M, K, bm, bn, As, Bs, acc);

    const int lane = threadIdx.x & 63, w = threadIdx.x >> 6;
    const int wr = w >> 1, wc = w & 1, l16 = lane & 15, lg = lane >> 4;
    const int row0 = bm + wr * 64, col0 = bn + wc * 64;
    float bv[4];
    #pragma unroll
    for (int fn = 0; fn < 4; ++fn) bv[fn] = bias[col0 + fn * 16 + l16];
    #pragma unroll
    for (int fm = 0; fm < 4; ++fm)
        #pragma unroll
        for (int i = 0; i < 4; ++i) {
            int gm = row0 + fm * 16 + lg * 4 + i;
            if (gm >= M) continue;
            #pragma unroll
            for (int fn = 0; fn < 4; ++fn)
                C[(size_t)gm * N + col0 + fn * 16 + l16] = acc[fm][fn][i] + bv[fn];
        }
}

// ---------------- fused attention: 2 edges per wave (lane halves), split-softmax merge, flat grid ----------------
__global__ __launch_bounds__(256)
void attn_fused_kernel(const unsigned char* __restrict__ qkvb,
                       const int* __restrict__ rp6, const int2* __restrict__ csr_es6,
                       const float* __restrict__ ewp, const float* __restrict__ ebp,
                       unsigned short* __restrict__ aggbf)
{
    constexpr size_t qoffB[3] = {0, 20000ull * 1024, 30000ull * 1024};
    constexpr size_t aoffE[3] = {0, 20000ull * 256, 30000ull * 256};
    constexpr int rpoff[6] = {0, 10001, 30002, 35003, 55004, 60005};
    constexpr int eAz[3] = {1, 0, 2}, eBz[3] = {3, 5, 4};    // incoming etypes per dst type
    constexpr int sAz[3] = {1, 0, 0}, sBz[3] = {2, 2, 1};    // their src node types

    const int gid = blockIdx.x * 4 + (threadIdx.x >> 6);     // 0..34999, exact grid
    int z, d;
    if (gid < 20000)      { z = 0; d = gid; }
    else if (gid < 30000) { z = 1; d = gid - 20000; }
    else                  { z = 2; d = gid - 30000; }
    const int t = threadIdx.x & 63;
    const int half = t >> 5, h = t & 31;
    // fold 1/sqrt(32) * log2(e) into the edge-linear coefficients (exp2-domain softmax)
    const float kfold = 0.17677669529663687f * 1.4426950408889634f;
    const float ewv = ewp[0] * kfold, ebv = ebp[0] * kfold;

    uint4 qw4 = *(const uint4*)(qkvb + qoffB[z] + (size_t)d * 1024 + 16 * h);
    const float qf0 = bf2f((unsigned short)(qw4.x & 0xffff));
    const float qf1 = bf2f((unsigned short)(qw4.x >> 16));
    const float qf2 = bf2f((unsigned short)(qw4.y & 0xffff));
    const float qf3 = bf2f((unsigned short)(qw4.y >> 16));
    const float qf4 = bf2f((unsigned short)(qw4.z & 0xffff));
    const float qf5 = bf2f((unsigned short)(qw4.z >> 16));
    const float qf6 = bf2f((unsigned short)(qw4.w & 0xffff));
    const float qf7 = bf2f((unsigned short)(qw4.w >> 16));

    float r0 = 0.f, r1 = 0.f, r2 = 0.f, r3 = 0.f, r4 = 0.f, r5 = 0.f, r6 = 0.f, r7 = 0.f;

    #pragma unroll
    for (int rr = 0; rr < 2; ++rr) {
        const int ei = rr == 0 ? eAz[z] : eBz[z];
        const int stp = rr == 0 ? sAz[z] : sBz[z];
        const int2* es = csr_es6 + (size_t)ei * 100000;
        const unsigned char* kvp = qkvb + qoffB[stp] + 512 + 16 * h;
        const int beg = rp6[rpoff[ei] + d], end = rp6[rpoff[ei] + d + 1];
        const int n = end - beg;
        if (n == 0) continue;

        float m = -1e30f, s = 0.f;
        float a0 = 0.f, a1 = 0.f, a2 = 0.f, a3 = 0.f, a4 = 0.f, a5 = 0.f, a6 = 0.f, a7 = 0.f;

        uint4 kv0 = {0,0,0,0}, kv1 = kv0;
        float sm0 = 0.f, sm1 = 0.f;
        {
            int i0 = half, i1 = 2 + half;
            if (i0 < n) { int2 e = es[beg + i0]; sm0 = __int_as_float(e.y); kv0 = *(const uint4*)(kvp + (size_t)e.x * 1024); }
            if (i1 < n) { int2 e = es[beg + i1]; sm1 = __int_as_float(e.y); kv1 = *(const uint4*)(kvp + (size_t)e.x * 1024); }
        }
        for (int jj = 0; jj < n; jj += 2) {
            uint4 kvc = kv0; float simc = sm0;
            kv0 = kv1; sm0 = sm1;
            int inx = jj + 4 + half;
            if (inx < n) { int2 e = es[beg + inx]; sm1 = __int_as_float(e.y); kv1 = *(const uint4*)(kvp + (size_t)e.x * 1024); }
            if (jj + half < n) {
                v2f k01 = __builtin_amdgcn_cvt_pk_f32_fp8((int)kvc.x, false);
                v2f k23 = __builtin_amdgcn_cvt_pk_f32_fp8((int)kvc.x, true);
                v2f k45 = __builtin_amdgcn_cvt_pk_f32_fp8((int)kvc.z, false);
                v2f k67 = __builtin_amdgcn_cvt_pk_f32_fp8((int)kvc.z, true);
                float dot = qf0 * k01[0] + qf1 * k01[1] + qf2 * k23[0] + qf3 * k23[1]
                          + qf4 * k45[0] + qf5 * k45[1] + qf6 * k67[0] + qf7 * k67[1];
                dot = dpp_xadd<0xB1>(dot);   // lane^1
                dot = dpp_xadd<0x4E>(dot);   // lane^2
                float sc = dot * fmaf(simc, ewv, ebv);
                float nm = fmaxf(m, sc);
                float rsc = exp2f(m - nm);
                float ex = exp2f(sc - nm);
                m = nm;
                s = fmaf(s, rsc, ex);
                v2f v01 = __builtin_amdgcn_cvt_pk_f32_fp8((int)kvc.y, false);
                v2f v23 = __builtin_amdgcn_cvt_pk_f32_fp8((int)kvc.y, true);
                v2f v45 = __builtin_amdgcn_cvt_pk_f32_fp8((int)kvc.w, false);
                v2f v67 = __builtin_amdgcn_cvt_pk_f32_fp8((int)kvc.w, true);
                a0 = fmaf(a0, rsc, ex * v01[0]);
                a1 = fmaf(a1, rsc, ex * v01[1]);
                a2 = fmaf(a2, rsc, ex * v23[0]);
                a3 = fmaf(a3, rsc, ex * v23[1]);
                a4 = fmaf(a4, rsc, ex * v45[0]);
                a5 = fmaf(a5, rsc, ex * v45[1]);
                a6 = fmaf(a6, rsc, ex * v67[0]);
                a7 = fmaf(a7, rsc, ex * v67[1]);
            }
        }
        // merge even/odd partial softmaxes across lane^32
        float mo = __shfl_xor(m, 32);
        float so = __shfl_xor(s, 32);
        float mm = fmaxf(m, mo);
        float rs = exp2f(m - mm), ro = exp2f(mo - mm);
        float stot = fmaf(s, rs, so * ro);
        float inv = 1.0f / stot;
        float o0 = __shfl_xor(a0, 32), o1 = __shfl_xor(a1, 32);
        float o2 = __shfl_xor(a2, 32), o3 = __shfl_xor(a3, 32);
        float o4 = __shfl_xor(a4, 32), o5 = __shfl_xor(a5, 32);
        float o6 = __shfl_xor(a6, 32), o7 = __shfl_xor(a7, 32);
        r0 += fmaf(a0, rs, o0 * ro) * inv;
        r1 += fmaf(a1, rs, o1 * ro) * inv;
        r2 += fmaf(a2, rs, o2 * ro) * inv;
        r3 += fmaf(a3, rs, o3 * ro) * inv;
        r4 += fmaf(a4, rs, o4 * ro) * inv;
        r5 += fmaf(a5, rs, o5 * ro) * inv;
        r6 += fmaf(a6, rs, o6 * ro) * inv;
        r7 += fmaf(a7, rs, o7 * ro) * inv;
    }

    if (half == 0) {
        uint4 o;
        o.x = (unsigned int)f2bf(r0) | ((unsigned int)f2bf(r1) << 16);
        o.y = (unsigned int)f2bf(r2) | ((unsigned int)f2bf(r3) << 16);
        o.z = (unsigned int)f2bf(r4) | ((unsigned int)f2bf(r5) << 16);
        o.w = (unsigned int)f2bf(r6) | ((unsigned int)f2bf(r7) << 16);
        *(uint4*)((unsigned char*)(aggbf + aoffE[z]) + (size_t)d * 512 + 16 * h) = o;
    }
}

// colsum: per-block partials, no atomics / no memset
__global__ void colsum_kernel(const unsigned short* __restrict__ hbf, float* __restrict__ part, int N)
{
    int c = threadIdx.x;
    float acc = 0.0f;
    for (int r = blockIdx.x; r < N; r += gridDim.x)
        acc += bf2f(hbf[(size_t)r * 256 + c]);
    part[(size_t)blockIdx.x * 256 + c] = acc;
}

__global__ __launch_bounds__(512)
void head_kernel(const float* __restrict__ part, float n_img,
                 const float* __restrict__ pred_w, const float* __restrict__ pred_b,
                 const float* __restrict__ head1_w, const float* __restrict__ head1_b,
                 const float* __restrict__ head_w, const float* __restrict__ head_b,
                 float* __restrict__ cvec)
{
    __shared__ float mean[256], o0[256], g[512];
    int t = threadIdx.x;
    if (t < 256) {
        float acc = 0.0f;
        for (int i = 0; i < 128; ++i) acc += part[(size_t)i * 256 + t];
        mean[t] = acc / n_img;
    }
    __syncthreads();
    if (t < 256) {
        float acc = pred_b[t];
        for (int k = 0; k < 256; ++k) acc += mean[k] * pred_w[k * 256 + t];
        o0[t] = acc;
    }
    __syncthreads();
    {
        float acc = head1_b[t];
        for (int k = 0; k < 256; ++k) acc += o0[k] * head1_w[k * 512 + t];
        g[t] = acc;
    }
    __syncthreads();
    {
        float acc = head_b[t];
        for (int k = 0; k < 512; ++k) acc += g[k] * head_w[k * 512 + t];
        cvec[t] = acc;
    }
}

extern "C" void kernel_launch(void* const* d_in, const int* in_sizes, int n_in,
                              void* d_out, int out_size, void* d_ws, size_t ws_size,
                              hipStream_t stream)
{
    const int NI = 20000, E = 100000;

    const float* feat[3] = {(const float*)d_in[0], (const float*)d_in[1], (const float*)d_in[2]};
    const float* adapt_w = (const float*)d_in[3];
    const float* adapt_b = (const float*)d_in[4];
    const float* k_w = (const float*)d_in[5];
    const float* k_b = (const float*)d_in[6];
    const float* q_w = (const float*)d_in[7];
    const float* q_b = (const float*)d_in[8];
    const float* v_w = (const float*)d_in[9];
    const float* v_b = (const float*)d_in[10];
    const float* a_w = (const float*)d_in[11];
    const float* a_b = (const float*)d_in[12];
    const float* e_w = (const float*)d_in[13];
    const float* e_b = (const float*)d_in[14];
    const float* skip = (const float*)d_in[15];
    const float* pred_w = (const float*)d_in[16];
    const float* pred_b = (const float*)d_in[17];
    const float* head1_w = (const float*)d_in[19];
    const float* head1_b = (const float*)d_in[20];
    const float* head_w = (const float*)d_in[21];
    const float* head_b = (const float*)d_in[22];

    GraphPtrs gp;
    for (int i = 0; i < 6; ++i) {
        gp.sim[i] = (const float*)d_in[23 + i];
        gp.src[i] = (const int*)d_in[29 + 2 * i];
        gp.dst[i] = (const int*)d_in[30 + 2 * i];
    }

    float* ws = (float*)d_ws;
    size_t off = 0;
    auto alloc = [&](size_t n) { float* p = ws + off; off += (n + 3) & ~(size_t)3; return p; };
    const size_t NTOT = 35000ull * 256;
    unsigned short* hbf   = (unsigned short*)alloc(NTOT / 2);
    unsigned short* aggbf = (unsigned short*)alloc(NTOT / 2);
    unsigned char* qkvb   = (unsigned char*)alloc(35000ull * 256);   // 1024 B per node
    unsigned short* fbf   = (unsigned short*)alloc(20000ull * 512 / 2);  // bf16 feats[0]
    float* cpart = alloc(128 * 256);
    float* cvec = alloc(512);
    int* deg6    = (int*)alloc(70000);
    int* cursor6 = (int*)alloc(70000);
    int* rp6     = (int*)alloc(70012);
    int2* csr_es6 = (int2*)alloc(1200000);
    unsigned short* adapt_wt = (unsigned short*)alloc(3 * 512 * 256 / 2);
    unsigned short* W3   = (unsigned short*)alloc(6ull * 768 * 256 / 2);  // [lt][768][256]
    unsigned short* a_wt = (unsigned short*)alloc(6 * 65536 / 2);
    float* bias768 = alloc(6 * 768);
    unsigned short* head_wt = (unsigned short*)alloc(512 * 512 / 2);

    // ---- CSR build ----
    hipMemsetAsync(deg6, 0, 70000 * sizeof(int), stream);
    hipLaunchKernelGGL(hist6_kernel, dim3((E + 255) / 256, 6), dim3(256), 0, stream, gp, deg6);
    hipLaunchKernelGGL(scan6_kernel, dim3(6), dim3(256), 0, stream, deg6, rp6, cursor6);
    hipLaunchKernelGGL(scatter6_kernel, dim3((E + 255) / 256, 6), dim3(256), 0, stream,
                       gp, cursor6, csr_es6);

    // ---- weights -> bf16 (single fused dispatch) ----
    PrepArgs pa;
    pa.adapt_w = adapt_w; pa.q_w = q_w; pa.k_w = k_w; pa.v_w = v_w;
    pa.a_w = a_w; pa.head_w = head_w;
    pa.q_b = q_b; pa.k_b = k_b; pa.v_b = v_b;
    pa.adapt_wt = adapt_wt; pa.W3 = W3; pa.a_wt = a_wt;
    pa.head_wt = head_wt; pa.bias768 = bias768;
    hipLaunchKernelGGL(prep_all_kernel, dim3(2194), dim3(256), 0, stream, pa);

    // ---- adapt (all 3 types in one dispatch; side-writes bf16 feat0 into fbf) ----
    Ptr3f fa; fa.p[0] = feat[0]; fa.p[1] = feat[1]; fa.p[2] = feat[2];
    hipLaunchKernelGGL(adapt_gemm3, dim3(2, 157, 3), dim3(256), 0, stream, fa, adapt_wt, adapt_b, hbf, fbf);

    for (int l = 0; l < 2; ++l) {
        hipLaunchKernelGGL(qkv_gemm3, dim3(6, 157, 3), dim3(256), 0, stream,
                           hbf, W3 + (size_t)l * 3 * 768 * 256, bias768 + (size_t)l * 3 * 768, qkvb);
        hipLaunchKernelGGL(attn_fused_kernel, dim3(8750), dim3(256), 0, stream,
                           qkvb, rp6, csr_es6, e_w + l, e_b + l, aggbf);
        hipLaunchKernelGGL(a_gemm3, dim3(2, 157, 3), dim3(256), 0, stream,
                           aggbf, a_wt + (size_t)l * 3 * 65536, a_b + (size_t)l * 3 * 256,
                           skip + l * 3, hbf);
    }

    hipLaunchKernelGGL(colsum_kernel, dim3(128), dim3(256), 0, stream, hbf, cpart, NI);
    hipLaunchKernelGGL(head_kernel, dim3(1), dim3(512), 0, stream,
                       cpart, (float)NI, pred_w, pred_b, head1_w, head1_b, head_w, head_b, cvec);

    // out = bf16(feats[0]) @ head_w + cvec
    hipLaunchKernelGGL(head_gemm, dim3(4, 157), dim3(256), 0, stream,
                       fbf, head_wt, cvec, (float*)d_out);
}